// Round 18
// baseline (30.023 us; speedup 1.0000x reference)
//
#include <hip/hip_runtime.h>
#include <stdint.h>

#define NDIM 1024
#define BATCH 16

typedef float fvec4 __attribute__((ext_vector_type(4)));

__device__ __forceinline__ float h2f(uint32_t bits16) {
    _Float16 h = __builtin_bit_cast(_Float16, (uint16_t)bits16);
    return (float)h;
}

// R18 = R17 (XCD swizzle: 36.9->29.2us, FETCH 67.7->36.5MB — read-locality
// confirmed as the binder) + R12's conflict-free apply halos (interior halos
// via shuffle, single predicated edge read; proven 3.93M->786K conflict drop).
// At 29us the ~60cy/step of 8-way-conflicted scalar ds_reads is now a
// meaningful fraction of the shortened step.
__global__ __launch_bounds__(256) void smallsm_fused(
    const float* __restrict__ image,
    const float* __restrict__ x,
    const float* __restrict__ w,
    const float* __restrict__ bias,
    float* __restrict__ out)
{
    __shared__ float Xlds[4][3][512];   // [wave][buf][6*72 used + pad] = 24576 B

    const int N = NDIM;
    const size_t NN = (size_t)N * N;
    const int tid  = threadIdx.x;
    const int wid  = tid >> 6;            // wave 0..3
    const int lane = tid & 63;
    const int tx   = lane & 15;           // 16 lanes in j (x4 px = 64 cols)
    const int g    = lane >> 4;           // row group 0..3 within wave

    // ---- XCD-aware bijective swizzle (nwg = 1024, 8 XCDs) ----
    // XCD = bid % 8 (round-robin dispatch). tile=(bid&7)*128+(bid>>3):
    // XCD k owns tiles [k*128,(k+1)*128) = block-rows [k*8,(k+1)*8) —
    // row re-reads between y-adjacent blocks stay XCD-local (512KB < 4MB L2).
    const int bid  = blockIdx.y * 16 + blockIdx.x;
    const int tile = (bid & 7) * 128 + (bid >> 3);
    const int bx   = tile & 15;           // column-tile 0..15
    const int by   = tile >> 4;           // row-tile 0..63

    const int jB   = bx * 64;
    const int jT   = jB + tx * 4;
    const int iW   = by * 16 + wid * 4;   // wave's first output row
    const int iT   = iW + g;

    const bool is_l = (tx == 0);
    const bool is_r = (tx == 15);

    // ---- staging source offsets: 2 global_load_lds per stage ----
    uint32_t soff0, soff1; bool sv0, sv1;
#pragma unroll
    for (int ii = 0; ii < 2; ++ii) {
        const int S    = ii * 64 + lane;
        const int row  = S / 18;
        const int slot = S - row * 18;
        const int colF = (slot < 16) ? slot * 4 : (slot == 16 ? -4 : 64);
        const int grow = iW - 1 + row;
        const int gcol = jB + colF;
        const bool v = (S < 108) && (grow >= 0) && (grow < N) &&
                       (gcol >= 0) && (gcol + 4 <= N);
        const uint32_t o = (uint32_t)(grow * N + gcol);
        if (ii == 0) { sv0 = v; soff0 = o; } else { sv1 = v; soff1 = o; }
    }

    auto stage = [&](int b, int buf) {
        const float* xb = x + (size_t)b * NN;
        float* lb = &Xlds[wid][buf][0];
        if (sv0)
            __builtin_amdgcn_global_load_lds(
                (const __attribute__((address_space(1))) void*)(xb + soff0),
                (__attribute__((address_space(3))) void*)(lb), 16, 0, 0);
        if (sv1)
            __builtin_amdgcn_global_load_lds(
                (const __attribute__((address_space(1))) void*)(xb + soff1),
                (__attribute__((address_space(3))) void*)(lb + 256), 16, 0, 0);
    };

    // ---- prologue: image loads (K-build input), then stages 0,1 ----
    const bool hpred = (is_l && jT > 0) || (is_r && jT + 4 < N);
    const int  hoff  = is_r ? (jT + 4) : (jT - 1);
    float im_m[3][4], im_h[3];
#pragma unroll
    for (int r = 0; r < 3; ++r) {
        const int row = iT - 1 + r;
        const bool rv = (row >= 0) && (row < N);
        const float* rp = image + (size_t)row * N;
        fvec4 mv = {0.f, 0.f, 0.f, 0.f};
        if (rv) mv = *reinterpret_cast<const fvec4*>(rp + jT);
        im_h[r] = (rv && hpred) ? rp[hoff] : 0.f;
        im_m[r][0] = mv.x; im_m[r][1] = mv.y; im_m[r][2] = mv.z; im_m[r][3] = mv.w;
    }
    __builtin_amdgcn_sched_barrier(0);
    stage(0, 0);
    stage(1, 1);
    __builtin_amdgcn_sched_barrier(0);

    // ---- build K (fp32), pack fp16x2 -> Kp[18] (runs under stage latency) ----
    uint32_t Kp[18];
    {
        float im[3][6];
#pragma unroll
        for (int r = 0; r < 3; ++r) {
            float left  = __shfl_up(im_m[r][3], 1);
            float right = __shfl_down(im_m[r][0], 1);
            if (is_l) left  = im_h[r];
            if (is_r) right = im_h[r];
            im[r][0] = left;       im[r][1] = im_m[r][0]; im[r][2] = im_m[r][1];
            im[r][3] = im_m[r][2]; im[r][4] = im_m[r][3]; im[r][5] = right;
        }
#pragma unroll
        for (int p = 0; p < 9; ++p) {
            const float bv = bias[p];
            float a0 = bv, a1 = bv, a2 = bv, a3 = bv;
#pragma unroll
            for (int m = 0; m < 3; ++m) {
#pragma unroll
                for (int n = 0; n < 3; ++n) {
                    const float wv = w[p * 9 + m * 3 + n];
                    a0 += wv * im[m][0 + n];
                    a1 += wv * im[m][1 + n];
                    a2 += wv * im[m][2 + n];
                    a3 += wv * im[m][3 + n];
                }
            }
            const uint16_t q0 = __builtin_bit_cast(uint16_t, (_Float16)a0);
            const uint16_t q1 = __builtin_bit_cast(uint16_t, (_Float16)a1);
            const uint16_t q2 = __builtin_bit_cast(uint16_t, (_Float16)a2);
            const uint16_t q3 = __builtin_bit_cast(uint16_t, (_Float16)a3);
            Kp[2 * p]     = (uint32_t)q0 | ((uint32_t)q1 << 16);
            Kp[2 * p + 1] = (uint32_t)q2 | ((uint32_t)q3 << 16);
        }
    }

    // ---- apply batch k from buffer buf (literal), store result ----
    // Interior halos via shuffle (conflict-free crossbar); only lanes {0,15}
    // of each 16-lane group do one merged LDS edge read (R12-validated:
    // conflicts 3.93M -> 786K).
    auto apply = [&](int k, int buf) {
        const float* base = &Xlds[wid][buf][0];
        float a0 = 0.f, a1 = 0.f, a2 = 0.f, a3 = 0.f;
#pragma unroll
        for (int r = 0; r < 3; ++r) {
            const float* rp = base + (g + r) * 72;
            const bool rv = ((unsigned)(iT - 1 + r) < (unsigned)N);
            fvec4 m = *reinterpret_cast<const fvec4*>(rp + 4 * tx);
            float edge = 0.f;
            if (is_l || is_r) edge = rp[is_r ? 68 : 67];
            float lft = __shfl_up(m.w, 1);     // lane tx-1's last element
            float rgt = __shfl_down(m.x, 1);   // lane tx+1's first element
            if (is_l) lft = (jB == 0)      ? 0.f : edge;
            if (is_r) rgt = (jB + 64 >= N) ? 0.f : edge;
            if (!rv) { m.x = 0.f; m.y = 0.f; m.z = 0.f; m.w = 0.f; lft = 0.f; rgt = 0.f; }
            const float wv[6] = { lft, m.x, m.y, m.z, m.w, rgt };
#pragma unroll
            for (int l = 0; l < 3; ++l) {
                const int p = 3 * r + l;
                const uint32_t u0 = Kp[2 * p], u1 = Kp[2 * p + 1];
                a0 += h2f(u0 & 0xffffu) * wv[l + 0];
                a1 += h2f(u0 >> 16)     * wv[l + 1];
                a2 += h2f(u1 & 0xffffu) * wv[l + 2];
                a3 += h2f(u1 >> 16)     * wv[l + 3];
            }
        }
        fvec4 res; res.x = a0; res.y = a1; res.z = a2; res.w = a3;
        fvec4* dst = reinterpret_cast<fvec4*>(
            out + (size_t)k * NN + (size_t)iT * N + jT);
        *dst = res;
    };

    // ---- barrier-free 16-batch pipeline (identical to R13/R17) ----
#define WAITV(NIMM) do {                                              \
        asm volatile("s_waitcnt vmcnt(" #NIMM ")" ::: "memory");      \
        __builtin_amdgcn_sched_barrier(0);                            \
    } while (0)
#define STEP(K_, BUFR, BUFW, NIMM) do {                               \
        WAITV(NIMM);                                                  \
        if ((K_) + 2 < BATCH) stage((K_) + 2, BUFW);                  \
        __builtin_amdgcn_sched_barrier(0);                            \
        apply((K_), BUFR);                                            \
    } while (0)

    STEP(0,  0, 2, 2);
    STEP(1,  1, 0, 3);
    STEP(2,  2, 1, 4);
    STEP(3,  0, 2, 4);
    STEP(4,  1, 0, 4);
    STEP(5,  2, 1, 4);
    STEP(6,  0, 2, 4);
    STEP(7,  1, 0, 4);
    STEP(8,  2, 1, 4);
    STEP(9,  0, 2, 4);
    STEP(10, 1, 0, 4);
    STEP(11, 2, 1, 4);
    STEP(12, 0, 2, 4);
    STEP(13, 1, 0, 4);
    STEP(14, 2, 0, 4);   // no stage(16); BUFW unused
    STEP(15, 0, 0, 2);   // no stage(17); only st13,st14 newer than s15
#undef STEP
#undef WAITV
}

extern "C" void kernel_launch(void* const* d_in, const int* in_sizes, int n_in,
                              void* d_out, int out_size, void* d_ws, size_t ws_size,
                              hipStream_t stream) {
    const float* image = (const float*)d_in[0];
    const float* x     = (const float*)d_in[1];
    const float* w     = (const float*)d_in[2];
    const float* bias  = (const float*)d_in[3];
    float* outp = (float*)d_out;

    dim3 grid(NDIM / 64, NDIM / 16, 1);
    dim3 block(256);
    hipLaunchKernelGGL(smallsm_fused, grid, block, 0, stream,
                       image, x, w, bias, outp);
}

// Round 19
// 29.767 us; speedup vs baseline: 1.0086x; 1.0086x over previous
//
#include <hip/hip_runtime.h>
#include <stdint.h>

#define NDIM 1024
#define BATCH 16
#define BCHUNK 8   // batches per block; grid.z = 2

typedef float fvec4 __attribute__((ext_vector_type(4)));

__device__ __forceinline__ float h2f(uint32_t bits16) {
    _Float16 h = __builtin_bit_cast(_Float16, (uint16_t)bits16);
    return (float)h;
}

// R19 = R17 (XCD swizzle, best 29.2us) + BCHUNK=8 for TLP.
// R17 proved the plateau was read-service locality (FETCH 67.7->36.5MB,
// -21% time). Remaining: occupancy 26%, VALUBusy 21% -> concurrency-starved.
// 2048 blocks -> up to 7 resident blocks/CU (LDS shaved to exact 432-float
// buffers, 20736 B/block) = up to 28 waves/CU vs 16. R11's BCHUNK=8 was
// neutral PRE-swizzle (service latency was the binder; TLP couldn't convert);
// post-swizzle it should convert directly. K built twice (once per z-slice,
// ~1us extra VALU; image reads L2-local). z-slices of the same row-band land
// on the same XCD (bid%8 invariant under +1024) so locality is preserved.
// Apply = R17's scalar-LDS-halo version (R18's shuffle halos regressed).
__global__ __launch_bounds__(256) void smallsm_fused(
    const float* __restrict__ image,
    const float* __restrict__ x,
    const float* __restrict__ w,
    const float* __restrict__ bias,
    float* __restrict__ out)
{
    __shared__ float Xlds[4][3][432];   // [wave][buf][108 vec4 slots] = 20736 B

    const int N = NDIM;
    const size_t NN = (size_t)N * N;
    const int tid  = threadIdx.x;
    const int wid  = tid >> 6;            // wave 0..3
    const int lane = tid & 63;
    const int tx   = lane & 15;           // 16 lanes in j (x4 px = 64 cols)
    const int g    = lane >> 4;           // row group 0..3 within wave

    // ---- XCD-aware bijective swizzle (per z-slice nwg = 1024, 8 XCDs) ----
    const int bid  = blockIdx.y * 16 + blockIdx.x;
    const int tile = (bid & 7) * 128 + (bid >> 3);
    const int bx   = tile & 15;           // column-tile 0..15
    const int by   = tile >> 4;           // row-tile 0..63

    const int jB   = bx * 64;
    const int jT   = jB + tx * 4;
    const int iW   = by * 16 + wid * 4;   // wave's first output row
    const int iT   = iW + g;
    const int b0   = blockIdx.z * BCHUNK;

    const bool is_l = (tx == 0);
    const bool is_r = (tx == 15);

    // ---- staging source offsets: 2 global_load_lds per stage ----
    uint32_t soff0, soff1; bool sv0, sv1;
#pragma unroll
    for (int ii = 0; ii < 2; ++ii) {
        const int S    = ii * 64 + lane;
        const int row  = S / 18;
        const int slot = S - row * 18;
        const int colF = (slot < 16) ? slot * 4 : (slot == 16 ? -4 : 64);
        const int grow = iW - 1 + row;
        const int gcol = jB + colF;
        const bool v = (S < 108) && (grow >= 0) && (grow < N) &&
                       (gcol >= 0) && (gcol + 4 <= N);
        const uint32_t o = (uint32_t)(grow * N + gcol);
        if (ii == 0) { sv0 = v; soff0 = o; } else { sv1 = v; soff1 = o; }
    }

    auto stage = [&](int b, int buf) {
        const float* xb = x + (size_t)(b0 + b) * NN;
        float* lb = &Xlds[wid][buf][0];
        if (sv0)
            __builtin_amdgcn_global_load_lds(
                (const __attribute__((address_space(1))) void*)(xb + soff0),
                (__attribute__((address_space(3))) void*)(lb), 16, 0, 0);
        if (sv1)
            __builtin_amdgcn_global_load_lds(
                (const __attribute__((address_space(1))) void*)(xb + soff1),
                (__attribute__((address_space(3))) void*)(lb + 256), 16, 0, 0);
    };

    // ---- prologue: image loads (K-build input), then stages 0,1 ----
    const bool hpred = (is_l && jT > 0) || (is_r && jT + 4 < N);
    const int  hoff  = is_r ? (jT + 4) : (jT - 1);
    float im_m[3][4], im_h[3];
#pragma unroll
    for (int r = 0; r < 3; ++r) {
        const int row = iT - 1 + r;
        const bool rv = (row >= 0) && (row < N);
        const float* rp = image + (size_t)row * N;
        fvec4 mv = {0.f, 0.f, 0.f, 0.f};
        if (rv) mv = *reinterpret_cast<const fvec4*>(rp + jT);
        im_h[r] = (rv && hpred) ? rp[hoff] : 0.f;
        im_m[r][0] = mv.x; im_m[r][1] = mv.y; im_m[r][2] = mv.z; im_m[r][3] = mv.w;
    }
    __builtin_amdgcn_sched_barrier(0);
    stage(0, 0);
    stage(1, 1);
    __builtin_amdgcn_sched_barrier(0);

    // ---- build K (fp32), pack fp16x2 -> Kp[18] (runs under stage latency) ----
    uint32_t Kp[18];
    {
        float im[3][6];
#pragma unroll
        for (int r = 0; r < 3; ++r) {
            float left  = __shfl_up(im_m[r][3], 1);
            float right = __shfl_down(im_m[r][0], 1);
            if (is_l) left  = im_h[r];
            if (is_r) right = im_h[r];
            im[r][0] = left;       im[r][1] = im_m[r][0]; im[r][2] = im_m[r][1];
            im[r][3] = im_m[r][2]; im[r][4] = im_m[r][3]; im[r][5] = right;
        }
#pragma unroll
        for (int p = 0; p < 9; ++p) {
            const float bv = bias[p];
            float a0 = bv, a1 = bv, a2 = bv, a3 = bv;
#pragma unroll
            for (int m = 0; m < 3; ++m) {
#pragma unroll
                for (int n = 0; n < 3; ++n) {
                    const float wv = w[p * 9 + m * 3 + n];
                    a0 += wv * im[m][0 + n];
                    a1 += wv * im[m][1 + n];
                    a2 += wv * im[m][2 + n];
                    a3 += wv * im[m][3 + n];
                }
            }
            const uint16_t q0 = __builtin_bit_cast(uint16_t, (_Float16)a0);
            const uint16_t q1 = __builtin_bit_cast(uint16_t, (_Float16)a1);
            const uint16_t q2 = __builtin_bit_cast(uint16_t, (_Float16)a2);
            const uint16_t q3 = __builtin_bit_cast(uint16_t, (_Float16)a3);
            Kp[2 * p]     = (uint32_t)q0 | ((uint32_t)q1 << 16);
            Kp[2 * p + 1] = (uint32_t)q2 | ((uint32_t)q3 << 16);
        }
    }

    // ---- apply batch k from buffer buf (literal), store result ----
    auto apply = [&](int k, int buf) {
        const float* base = &Xlds[wid][buf][0];
        float a0 = 0.f, a1 = 0.f, a2 = 0.f, a3 = 0.f;
#pragma unroll
        for (int r = 0; r < 3; ++r) {
            const float* rp = base + (g + r) * 72;
            const bool rv = ((unsigned)(iT - 1 + r) < (unsigned)N);
            fvec4 m = *reinterpret_cast<const fvec4*>(rp + 4 * tx);
            float lft = is_l ? rp[67] : rp[4 * tx - 1];
            float rgt = is_r ? rp[68] : rp[4 * tx + 4];
            if (is_l && jB == 0)      lft = 0.f;
            if (is_r && jB + 64 >= N) rgt = 0.f;
            if (!rv) { m.x = 0.f; m.y = 0.f; m.z = 0.f; m.w = 0.f; lft = 0.f; rgt = 0.f; }
            const float wv[6] = { lft, m.x, m.y, m.z, m.w, rgt };
#pragma unroll
            for (int l = 0; l < 3; ++l) {
                const int p = 3 * r + l;
                const uint32_t u0 = Kp[2 * p], u1 = Kp[2 * p + 1];
                a0 += h2f(u0 & 0xffffu) * wv[l + 0];
                a1 += h2f(u0 >> 16)     * wv[l + 1];
                a2 += h2f(u1 & 0xffffu) * wv[l + 2];
                a3 += h2f(u1 >> 16)     * wv[l + 3];
            }
        }
        fvec4 res; res.x = a0; res.y = a1; res.z = a2; res.w = a3;
        fvec4* dst = reinterpret_cast<fvec4*>(
            out + (size_t)(b0 + k) * NN + (size_t)iT * N + jT);
        *dst = res;
    };

    // ---- barrier-free 8-batch pipeline (R11's validated vmcnt table) ----
#define WAITV(NIMM) do {                                              \
        asm volatile("s_waitcnt vmcnt(" #NIMM ")" ::: "memory");      \
        __builtin_amdgcn_sched_barrier(0);                            \
    } while (0)
#define STEP(K_, BUFR, BUFW, NIMM) do {                               \
        WAITV(NIMM);                                                  \
        if ((K_) + 2 < BCHUNK) stage((K_) + 2, BUFW);                 \
        __builtin_amdgcn_sched_barrier(0);                            \
        apply((K_), BUFR);                                            \
    } while (0)

    STEP(0, 0, 2, 2);
    STEP(1, 1, 0, 3);
    STEP(2, 2, 1, 4);
    STEP(3, 0, 2, 4);
    STEP(4, 1, 0, 4);
    STEP(5, 2, 1, 4);
    STEP(6, 0, 0, 4);   // no stage(8); BUFW unused
    STEP(7, 1, 0, 2);   // no stage(9); only st(5),st(6) newer than s(7)
#undef STEP
#undef WAITV
}

extern "C" void kernel_launch(void* const* d_in, const int* in_sizes, int n_in,
                              void* d_out, int out_size, void* d_ws, size_t ws_size,
                              hipStream_t stream) {
    const float* image = (const float*)d_in[0];
    const float* x     = (const float*)d_in[1];
    const float* w     = (const float*)d_in[2];
    const float* bias  = (const float*)d_in[3];
    float* outp = (float*)d_out;

    dim3 grid(NDIM / 64, NDIM / 16, BATCH / BCHUNK);
    dim3 block(256);
    hipLaunchKernelGGL(smallsm_fused, grid, block, 0, stream,
                       image, x, w, bias, outp);
}

// Round 20
// 28.072 us; speedup vs baseline: 1.0695x; 1.0604x over previous
//
#include <hip/hip_runtime.h>
#include <stdint.h>

#define NDIM 1024
#define BATCH 16

typedef float fvec4 __attribute__((ext_vector_type(4)));

__device__ __forceinline__ float h2f(uint32_t bits16) {
    _Float16 h = __builtin_bit_cast(_Float16, (uint16_t)bits16);
    return (float)h;
}

// R20 = R17 (XCD swizzle, best 29.2us) + prefetch depth 2 -> 4 (5 buffers).
// R12's depth-3 null was measured in the PRE-swizzle regime where locality
// (not depth) was the binder — regime-mismatched null. Post-swizzle the step
// is ~4400cy with ~3400cy of stall; depth-4 doubles the load-service horizon
// (2->4 steps) AND the store-retirement slack (vmcnt is one in-order counter,
// so load waits transitively force old stores retired). Steady wait vmcnt(10)
// = 3 in-flight stages x2 loads + 4 interleaved stores.
__global__ __launch_bounds__(256) void smallsm_fused(
    const float* __restrict__ image,
    const float* __restrict__ x,
    const float* __restrict__ w,
    const float* __restrict__ bias,
    float* __restrict__ out)
{
    __shared__ float Xlds[4][5][432];   // [wave][buf][108 vec4 slots] = 34560 B

    const int N = NDIM;
    const size_t NN = (size_t)N * N;
    const int tid  = threadIdx.x;
    const int wid  = tid >> 6;            // wave 0..3
    const int lane = tid & 63;
    const int tx   = lane & 15;           // 16 lanes in j (x4 px = 64 cols)
    const int g    = lane >> 4;           // row group 0..3 within wave

    // ---- XCD-aware bijective swizzle (nwg = 1024, 8 XCDs) ----
    const int bid  = blockIdx.y * 16 + blockIdx.x;
    const int tile = (bid & 7) * 128 + (bid >> 3);
    const int bx   = tile & 15;           // column-tile 0..15
    const int by   = tile >> 4;           // row-tile 0..63

    const int jB   = bx * 64;
    const int jT   = jB + tx * 4;
    const int iW   = by * 16 + wid * 4;   // wave's first output row
    const int iT   = iW + g;

    const bool is_l = (tx == 0);
    const bool is_r = (tx == 15);

    // ---- staging source offsets: 2 global_load_lds per stage ----
    uint32_t soff0, soff1; bool sv0, sv1;
#pragma unroll
    for (int ii = 0; ii < 2; ++ii) {
        const int S    = ii * 64 + lane;
        const int row  = S / 18;
        const int slot = S - row * 18;
        const int colF = (slot < 16) ? slot * 4 : (slot == 16 ? -4 : 64);
        const int grow = iW - 1 + row;
        const int gcol = jB + colF;
        const bool v = (S < 108) && (grow >= 0) && (grow < N) &&
                       (gcol >= 0) && (gcol + 4 <= N);
        const uint32_t o = (uint32_t)(grow * N + gcol);
        if (ii == 0) { sv0 = v; soff0 = o; } else { sv1 = v; soff1 = o; }
    }

    auto stage = [&](int b, int buf) {
        const float* xb = x + (size_t)b * NN;
        float* lb = &Xlds[wid][buf][0];
        if (sv0)
            __builtin_amdgcn_global_load_lds(
                (const __attribute__((address_space(1))) void*)(xb + soff0),
                (__attribute__((address_space(3))) void*)(lb), 16, 0, 0);
        if (sv1)
            __builtin_amdgcn_global_load_lds(
                (const __attribute__((address_space(1))) void*)(xb + soff1),
                (__attribute__((address_space(3))) void*)(lb + 256), 16, 0, 0);
    };

    // ---- prologue: image loads (K-build input), then stages 0..3 ----
    const bool hpred = (is_l && jT > 0) || (is_r && jT + 4 < N);
    const int  hoff  = is_r ? (jT + 4) : (jT - 1);
    float im_m[3][4], im_h[3];
#pragma unroll
    for (int r = 0; r < 3; ++r) {
        const int row = iT - 1 + r;
        const bool rv = (row >= 0) && (row < N);
        const float* rp = image + (size_t)row * N;
        fvec4 mv = {0.f, 0.f, 0.f, 0.f};
        if (rv) mv = *reinterpret_cast<const fvec4*>(rp + jT);
        im_h[r] = (rv && hpred) ? rp[hoff] : 0.f;
        im_m[r][0] = mv.x; im_m[r][1] = mv.y; im_m[r][2] = mv.z; im_m[r][3] = mv.w;
    }
    __builtin_amdgcn_sched_barrier(0);
    stage(0, 0);
    stage(1, 1);
    stage(2, 2);
    stage(3, 3);
    __builtin_amdgcn_sched_barrier(0);

    // ---- build K (fp32), pack fp16x2 -> Kp[18] (runs under stage latency) ----
    uint32_t Kp[18];
    {
        float im[3][6];
#pragma unroll
        for (int r = 0; r < 3; ++r) {
            float left  = __shfl_up(im_m[r][3], 1);
            float right = __shfl_down(im_m[r][0], 1);
            if (is_l) left  = im_h[r];
            if (is_r) right = im_h[r];
            im[r][0] = left;       im[r][1] = im_m[r][0]; im[r][2] = im_m[r][1];
            im[r][3] = im_m[r][2]; im[r][4] = im_m[r][3]; im[r][5] = right;
        }
#pragma unroll
        for (int p = 0; p < 9; ++p) {
            const float bv = bias[p];
            float a0 = bv, a1 = bv, a2 = bv, a3 = bv;
#pragma unroll
            for (int m = 0; m < 3; ++m) {
#pragma unroll
                for (int n = 0; n < 3; ++n) {
                    const float wv = w[p * 9 + m * 3 + n];
                    a0 += wv * im[m][0 + n];
                    a1 += wv * im[m][1 + n];
                    a2 += wv * im[m][2 + n];
                    a3 += wv * im[m][3 + n];
                }
            }
            const uint16_t q0 = __builtin_bit_cast(uint16_t, (_Float16)a0);
            const uint16_t q1 = __builtin_bit_cast(uint16_t, (_Float16)a1);
            const uint16_t q2 = __builtin_bit_cast(uint16_t, (_Float16)a2);
            const uint16_t q3 = __builtin_bit_cast(uint16_t, (_Float16)a3);
            Kp[2 * p]     = (uint32_t)q0 | ((uint32_t)q1 << 16);
            Kp[2 * p + 1] = (uint32_t)q2 | ((uint32_t)q3 << 16);
        }
    }

    // ---- apply batch k from buffer buf (literal), store result ----
    auto apply = [&](int k, int buf) {
        const float* base = &Xlds[wid][buf][0];
        float a0 = 0.f, a1 = 0.f, a2 = 0.f, a3 = 0.f;
#pragma unroll
        for (int r = 0; r < 3; ++r) {
            const float* rp = base + (g + r) * 72;
            const bool rv = ((unsigned)(iT - 1 + r) < (unsigned)N);
            fvec4 m = *reinterpret_cast<const fvec4*>(rp + 4 * tx);
            float lft = is_l ? rp[67] : rp[4 * tx - 1];
            float rgt = is_r ? rp[68] : rp[4 * tx + 4];
            if (is_l && jB == 0)      lft = 0.f;
            if (is_r && jB + 64 >= N) rgt = 0.f;
            if (!rv) { m.x = 0.f; m.y = 0.f; m.z = 0.f; m.w = 0.f; lft = 0.f; rgt = 0.f; }
            const float wv[6] = { lft, m.x, m.y, m.z, m.w, rgt };
#pragma unroll
            for (int l = 0; l < 3; ++l) {
                const int p = 3 * r + l;
                const uint32_t u0 = Kp[2 * p], u1 = Kp[2 * p + 1];
                a0 += h2f(u0 & 0xffffu) * wv[l + 0];
                a1 += h2f(u0 >> 16)     * wv[l + 1];
                a2 += h2f(u1 & 0xffffu) * wv[l + 2];
                a3 += h2f(u1 >> 16)     * wv[l + 3];
            }
        }
        fvec4 res; res.x = a0; res.y = a1; res.z = a2; res.w = a3;
        fvec4* dst = reinterpret_cast<fvec4*>(
            out + (size_t)k * NN + (size_t)iT * N + jT);
        *dst = res;
    };

    // ---- barrier-free depth-4 pipeline, 16 batches, bufs mod 5.
    // Step k: WAIT(stage(k) done) -> stage(k+4) -> apply(k){store(k)}.
    // Steady: ops newer than s(k)'s last load = 3 stages x2 + 4 stores = 10.
    // Prologue ramps 6,7,8,9; tail drains 10,8,6,4 (re-derived per order).
#define WAITV(NIMM) do {                                              \
        asm volatile("s_waitcnt vmcnt(" #NIMM ")" ::: "memory");      \
        __builtin_amdgcn_sched_barrier(0);                            \
    } while (0)
#define STEP(K_, BUFR, BUFW, NIMM) do {                               \
        WAITV(NIMM);                                                  \
        if ((K_) + 4 < BATCH) stage((K_) + 4, BUFW);                  \
        __builtin_amdgcn_sched_barrier(0);                            \
        apply((K_), BUFR);                                            \
    } while (0)

    STEP(0,  0, 4, 6);
    STEP(1,  1, 0, 7);
    STEP(2,  2, 1, 8);
    STEP(3,  3, 2, 9);
    STEP(4,  4, 3, 10);
    STEP(5,  0, 4, 10);
    STEP(6,  1, 0, 10);
    STEP(7,  2, 1, 10);
    STEP(8,  3, 2, 10);
    STEP(9,  4, 3, 10);
    STEP(10, 0, 4, 10);
    STEP(11, 1, 0, 10);
    STEP(12, 2, 0, 10);  // no stage(16); BUFW unused
    STEP(13, 3, 0, 8);
    STEP(14, 4, 0, 6);
    STEP(15, 0, 0, 4);
#undef STEP
#undef WAITV
}

extern "C" void kernel_launch(void* const* d_in, const int* in_sizes, int n_in,
                              void* d_out, int out_size, void* d_ws, size_t ws_size,
                              hipStream_t stream) {
    const float* image = (const float*)d_in[0];
    const float* x     = (const float*)d_in[1];
    const float* w     = (const float*)d_in[2];
    const float* bias  = (const float*)d_in[3];
    float* outp = (float*)d_out;

    dim3 grid(NDIM / 64, NDIM / 16, 1);
    dim3 block(256);
    hipLaunchKernelGGL(smallsm_fused, grid, block, 0, stream,
                       image, x, w, bias, outp);
}

// Round 21
// 28.069 us; speedup vs baseline: 1.0696x; 1.0001x over previous
//
#include <hip/hip_runtime.h>
#include <stdint.h>

#define NDIM 1024
#define BATCH 16

typedef float fvec4 __attribute__((ext_vector_type(4)));

__device__ __forceinline__ float h2f(uint32_t bits16) {
    _Float16 h = __builtin_bit_cast(_Float16, (uint16_t)bits16);
    return (float)h;
}

// R21 = R20 (XCD swizzle + depth-4, 28.1us) + nontemporal output stores.
// Post-swizzle, writes are 65.5 of ~102MB HBM traffic; plain stores
// write-allocate in the 4MB XCD L2 and evict the x rows whose L2 residency
// the swizzle bought (FETCH 36.5MB = ~70% x re-read hit rate). nt keeps the
// write stream out of L2, protecting x residency. Pre-swizzle A/B already
// gave nt a small edge (R10 35.9 vs R13 36.9).
__global__ __launch_bounds__(256) void smallsm_fused(
    const float* __restrict__ image,
    const float* __restrict__ x,
    const float* __restrict__ w,
    const float* __restrict__ bias,
    float* __restrict__ out)
{
    __shared__ float Xlds[4][5][432];   // [wave][buf][108 vec4 slots] = 34560 B

    const int N = NDIM;
    const size_t NN = (size_t)N * N;
    const int tid  = threadIdx.x;
    const int wid  = tid >> 6;            // wave 0..3
    const int lane = tid & 63;
    const int tx   = lane & 15;           // 16 lanes in j (x4 px = 64 cols)
    const int g    = lane >> 4;           // row group 0..3 within wave

    // ---- XCD-aware bijective swizzle (nwg = 1024, 8 XCDs) ----
    const int bid  = blockIdx.y * 16 + blockIdx.x;
    const int tile = (bid & 7) * 128 + (bid >> 3);
    const int bx   = tile & 15;           // column-tile 0..15
    const int by   = tile >> 4;           // row-tile 0..63

    const int jB   = bx * 64;
    const int jT   = jB + tx * 4;
    const int iW   = by * 16 + wid * 4;   // wave's first output row
    const int iT   = iW + g;

    const bool is_l = (tx == 0);
    const bool is_r = (tx == 15);

    // ---- staging source offsets: 2 global_load_lds per stage ----
    uint32_t soff0, soff1; bool sv0, sv1;
#pragma unroll
    for (int ii = 0; ii < 2; ++ii) {
        const int S    = ii * 64 + lane;
        const int row  = S / 18;
        const int slot = S - row * 18;
        const int colF = (slot < 16) ? slot * 4 : (slot == 16 ? -4 : 64);
        const int grow = iW - 1 + row;
        const int gcol = jB + colF;
        const bool v = (S < 108) && (grow >= 0) && (grow < N) &&
                       (gcol >= 0) && (gcol + 4 <= N);
        const uint32_t o = (uint32_t)(grow * N + gcol);
        if (ii == 0) { sv0 = v; soff0 = o; } else { sv1 = v; soff1 = o; }
    }

    auto stage = [&](int b, int buf) {
        const float* xb = x + (size_t)b * NN;
        float* lb = &Xlds[wid][buf][0];
        if (sv0)
            __builtin_amdgcn_global_load_lds(
                (const __attribute__((address_space(1))) void*)(xb + soff0),
                (__attribute__((address_space(3))) void*)(lb), 16, 0, 0);
        if (sv1)
            __builtin_amdgcn_global_load_lds(
                (const __attribute__((address_space(1))) void*)(xb + soff1),
                (__attribute__((address_space(3))) void*)(lb + 256), 16, 0, 0);
    };

    // ---- prologue: image loads (K-build input), then stages 0..3 ----
    const bool hpred = (is_l && jT > 0) || (is_r && jT + 4 < N);
    const int  hoff  = is_r ? (jT + 4) : (jT - 1);
    float im_m[3][4], im_h[3];
#pragma unroll
    for (int r = 0; r < 3; ++r) {
        const int row = iT - 1 + r;
        const bool rv = (row >= 0) && (row < N);
        const float* rp = image + (size_t)row * N;
        fvec4 mv = {0.f, 0.f, 0.f, 0.f};
        if (rv) mv = *reinterpret_cast<const fvec4*>(rp + jT);
        im_h[r] = (rv && hpred) ? rp[hoff] : 0.f;
        im_m[r][0] = mv.x; im_m[r][1] = mv.y; im_m[r][2] = mv.z; im_m[r][3] = mv.w;
    }
    __builtin_amdgcn_sched_barrier(0);
    stage(0, 0);
    stage(1, 1);
    stage(2, 2);
    stage(3, 3);
    __builtin_amdgcn_sched_barrier(0);

    // ---- build K (fp32), pack fp16x2 -> Kp[18] (runs under stage latency) ----
    uint32_t Kp[18];
    {
        float im[3][6];
#pragma unroll
        for (int r = 0; r < 3; ++r) {
            float left  = __shfl_up(im_m[r][3], 1);
            float right = __shfl_down(im_m[r][0], 1);
            if (is_l) left  = im_h[r];
            if (is_r) right = im_h[r];
            im[r][0] = left;       im[r][1] = im_m[r][0]; im[r][2] = im_m[r][1];
            im[r][3] = im_m[r][2]; im[r][4] = im_m[r][3]; im[r][5] = right;
        }
#pragma unroll
        for (int p = 0; p < 9; ++p) {
            const float bv = bias[p];
            float a0 = bv, a1 = bv, a2 = bv, a3 = bv;
#pragma unroll
            for (int m = 0; m < 3; ++m) {
#pragma unroll
                for (int n = 0; n < 3; ++n) {
                    const float wv = w[p * 9 + m * 3 + n];
                    a0 += wv * im[m][0 + n];
                    a1 += wv * im[m][1 + n];
                    a2 += wv * im[m][2 + n];
                    a3 += wv * im[m][3 + n];
                }
            }
            const uint16_t q0 = __builtin_bit_cast(uint16_t, (_Float16)a0);
            const uint16_t q1 = __builtin_bit_cast(uint16_t, (_Float16)a1);
            const uint16_t q2 = __builtin_bit_cast(uint16_t, (_Float16)a2);
            const uint16_t q3 = __builtin_bit_cast(uint16_t, (_Float16)a3);
            Kp[2 * p]     = (uint32_t)q0 | ((uint32_t)q1 << 16);
            Kp[2 * p + 1] = (uint32_t)q2 | ((uint32_t)q3 << 16);
        }
    }

    // ---- apply batch k from buffer buf (literal), store result ----
    auto apply = [&](int k, int buf) {
        const float* base = &Xlds[wid][buf][0];
        float a0 = 0.f, a1 = 0.f, a2 = 0.f, a3 = 0.f;
#pragma unroll
        for (int r = 0; r < 3; ++r) {
            const float* rp = base + (g + r) * 72;
            const bool rv = ((unsigned)(iT - 1 + r) < (unsigned)N);
            fvec4 m = *reinterpret_cast<const fvec4*>(rp + 4 * tx);
            float lft = is_l ? rp[67] : rp[4 * tx - 1];
            float rgt = is_r ? rp[68] : rp[4 * tx + 4];
            if (is_l && jB == 0)      lft = 0.f;
            if (is_r && jB + 64 >= N) rgt = 0.f;
            if (!rv) { m.x = 0.f; m.y = 0.f; m.z = 0.f; m.w = 0.f; lft = 0.f; rgt = 0.f; }
            const float wv[6] = { lft, m.x, m.y, m.z, m.w, rgt };
#pragma unroll
            for (int l = 0; l < 3; ++l) {
                const int p = 3 * r + l;
                const uint32_t u0 = Kp[2 * p], u1 = Kp[2 * p + 1];
                a0 += h2f(u0 & 0xffffu) * wv[l + 0];
                a1 += h2f(u0 >> 16)     * wv[l + 1];
                a2 += h2f(u1 & 0xffffu) * wv[l + 2];
                a3 += h2f(u1 >> 16)     * wv[l + 3];
            }
        }
        fvec4 res; res.x = a0; res.y = a1; res.z = a2; res.w = a3;
        fvec4* dst = reinterpret_cast<fvec4*>(
            out + (size_t)k * NN + (size_t)iT * N + jT);
        __builtin_nontemporal_store(res, dst);   // R21: nt store
    };

    // ---- barrier-free depth-4 pipeline, 16 batches, bufs mod 5 (R20) ----
#define WAITV(NIMM) do {                                              \
        asm volatile("s_waitcnt vmcnt(" #NIMM ")" ::: "memory");      \
        __builtin_amdgcn_sched_barrier(0);                            \
    } while (0)
#define STEP(K_, BUFR, BUFW, NIMM) do {                               \
        WAITV(NIMM);                                                  \
        if ((K_) + 4 < BATCH) stage((K_) + 4, BUFW);                  \
        __builtin_amdgcn_sched_barrier(0);                            \
        apply((K_), BUFR);                                            \
    } while (0)

    STEP(0,  0, 4, 6);
    STEP(1,  1, 0, 7);
    STEP(2,  2, 1, 8);
    STEP(3,  3, 2, 9);
    STEP(4,  4, 3, 10);
    STEP(5,  0, 4, 10);
    STEP(6,  1, 0, 10);
    STEP(7,  2, 1, 10);
    STEP(8,  3, 2, 10);
    STEP(9,  4, 3, 10);
    STEP(10, 0, 4, 10);
    STEP(11, 1, 0, 10);
    STEP(12, 2, 0, 10);  // no stage(16); BUFW unused
    STEP(13, 3, 0, 8);
    STEP(14, 4, 0, 6);
    STEP(15, 0, 0, 4);
#undef STEP
#undef WAITV
}

extern "C" void kernel_launch(void* const* d_in, const int* in_sizes, int n_in,
                              void* d_out, int out_size, void* d_ws, size_t ws_size,
                              hipStream_t stream) {
    const float* image = (const float*)d_in[0];
    const float* x     = (const float*)d_in[1];
    const float* w     = (const float*)d_in[2];
    const float* bias  = (const float*)d_in[3];
    float* outp = (float*)d_out;

    dim3 grid(NDIM / 64, NDIM / 16, 1);
    dim3 block(256);
    hipLaunchKernelGGL(smallsm_fused, grid, block, 0, stream,
                       image, x, w, bias, outp);
}